// Round 7
// baseline (259.349 us; speedup 1.0000x reference)
//
#include <hip/hip_runtime.h>

// QuantAttnBlock on gfx950, round 15: k_qpv VALU-diet. Same schedule as r14
// (2-deep pipeline, V-direct, split QK chains, 1024 thr) but:
//  - strength-reduced global pointers (kld += 16384, vld += 64) instead of
//    per-iter (mt+2)*... index arithmetic;
//  - cur -> (mt & 1) + #pragma unroll 2: compile-time buffer selection per
//    unrolled body, register rotations absorbed by renaming;
// Numerics identical (verified absmax ~0.0234).

#define Bb 4
#define Cc 256
#define Nn 4096
#define NGRP 32
#define LOG2E 1.4426950408889634f

typedef unsigned short u16;
typedef unsigned int   u32;
typedef unsigned char  u8;
typedef __attribute__((ext_vector_type(8))) short bf16x8;
typedef __attribute__((ext_vector_type(4))) float f32x4;
typedef __attribute__((ext_vector_type(4))) int   i32x4;

#define MFMA16(a,b,c)    __builtin_amdgcn_mfma_f32_16x16x32_bf16((a),(b),(c),0,0,0)
#define MFMA_I8(a,b,c)   __builtin_amdgcn_mfma_i32_16x16x64_i8((a),(b),(c),0,0,0)
#define EXP2F(x)         __builtin_amdgcn_exp2f(x)

static __device__ __forceinline__ u16 f2bf(float x){
  u32 u = __float_as_uint(x);
  u += 0x7fffu + ((u >> 16) & 1u);
  return (u16)(u >> 16);
}
static __device__ __forceinline__ float bf2f(u16 h){ return __uint_as_float(((u32)h) << 16); }

union U64c { u16 u[4]; uint2 v; };

// ---------------- GroupNorm stats ----------------
__global__ __launch_bounds__(256) void k_gn_stats(const float* __restrict__ x,
                                                  float* __restrict__ mu, float* __restrict__ rs){
  int bg = blockIdx.x;
  const float4* p = (const float4*)(x + (size_t)bg * (8 * Nn));
  float s = 0.f, q = 0.f;
  for (int i = threadIdx.x; i < 8*Nn/4; i += 256){
    float4 v = p[i];
    s += v.x + v.y + v.z + v.w;
    q += v.x*v.x + v.y*v.y + v.z*v.z + v.w*v.w;
  }
  __shared__ float rsum[256], rsq[256];
  rsum[threadIdx.x] = s; rsq[threadIdx.x] = q;
  __syncthreads();
  for (int off = 128; off > 0; off >>= 1){
    if (threadIdx.x < off){ rsum[threadIdx.x] += rsum[threadIdx.x+off]; rsq[threadIdx.x] += rsq[threadIdx.x+off]; }
    __syncthreads();
  }
  if (threadIdx.x == 0){
    const float inv = 1.0f / (8*Nn);
    float m = rsum[0]*inv;
    float var = rsq[0]*inv - m*m;
    mu[bg] = m; rs[bg] = rsqrtf(var + 1e-6f);
  }
}

// ------------- weight split: 4 matrices f32 -> hi/lo bf16 -------------
__global__ __launch_bounds__(256) void k_wsplit(const float* __restrict__ wq, const float* __restrict__ wk,
                                                const float* __restrict__ wv, const float* __restrict__ wp,
                                                u16* __restrict__ WH, u16* __restrict__ WL){
  int gid = blockIdx.x*256 + threadIdx.x;
  int mat = gid >> 16, idx = gid & 65535;
  const float* src = (mat == 0) ? wq : (mat == 1) ? wk : (mat == 2) ? wv : wp;
  float w = src[idx];
  u16 h = f2bf(w);
  WH[gid] = h;
  WL[gid] = f2bf(w - bf2f(h));
}

// ------------- GroupNorm apply + transpose -> hT hi/lo [b][n][c] -------------
__global__ __launch_bounds__(256) void k_gn_apply(const float* __restrict__ x,
                                                  const float* __restrict__ gsc, const float* __restrict__ gbi,
                                                  const float* __restrict__ mu, const float* __restrict__ rs,
                                                  u16* __restrict__ hhi, u16* __restrict__ hlo){
  int nt = blockIdx.x, ct = blockIdx.y, b = blockIdx.z;
  int n0 = nt*64, c0 = ct*64;
  __shared__ float yt[64*65];
  __shared__ float sa[64], sb[64];
  int t = threadIdx.x;
  if (t < 64){
    int c = c0 + t;
    int bg = b*NGRP + (c >> 3);
    float a = rs[bg] * gsc[c];
    sa[t] = a;
    sb[t] = gbi[c] - mu[bg]*a;
  }
  __syncthreads();
  #pragma unroll
  for (int j = 0; j < 4; ++j){
    int id = t + j*256;
    int r = id >> 4, cq = id & 15;
    float4 v = *(const float4*)(x + ((size_t)b*Cc + c0 + r)*Nn + n0 + cq*4);
    float a = sa[r], bb = sb[r];
    yt[r*65 + cq*4 + 0] = v.x*a + bb;
    yt[r*65 + cq*4 + 1] = v.y*a + bb;
    yt[r*65 + cq*4 + 2] = v.z*a + bb;
    yt[r*65 + cq*4 + 3] = v.w*a + bb;
  }
  __syncthreads();
  int nl = t >> 2, cg = (t & 3) * 16;
  size_t base = ((size_t)b*Nn + n0 + nl)*Cc + c0 + cg;
  #pragma unroll
  for (int half = 0; half < 2; ++half){
    union { u16 u[8]; uint4 v; } Ph, Pl;
    #pragma unroll
    for (int u = 0; u < 8; ++u){
      float y = yt[(cg + half*8 + u)*65 + nl];
      u16 h = f2bf(y);
      Ph.u[u] = h; Pl.u[u] = f2bf(y - bf2f(h));
    }
    *(uint4*)(hhi + base + half*8) = Ph.v;
    *(uint4*)(hlo + base + half*8) = Pl.v;
  }
}

// ------------- Fused QKV conv GEMM (bf16 hi/lo, ~fp32 accurate) -------------
__global__ __launch_bounds__(256) void k_convqkv(const u16* __restrict__ WH, const u16* __restrict__ WL,
                                                 const u16* __restrict__ Hhi, const u16* __restrict__ Hlo,
                                                 const float* __restrict__ bq, const float* __restrict__ bk,
                                                 const float* __restrict__ bv,
                                                 const float* __restrict__ dq, const float* __restrict__ zq,
                                                 const float* __restrict__ dk, const float* __restrict__ zk,
                                                 const float* __restrict__ dv, const float* __restrict__ zv,
                                                 u8* __restrict__ qT8, u8* __restrict__ kT8,
                                                 u8* __restrict__ v8){
  int nt = blockIdx.x, ot = blockIdx.y, b = blockIdx.z;
  __shared__ u16 Lh[64*256], Ll[64*256];
  int t = threadIdx.x, lane = t & 63, wave = t >> 6;
  int lo16 = lane & 15, quad = lane >> 4;
  int o0 = ot*64 + wave*16;

  {
    const u16* hb = Hhi + ((size_t)b*Nn + nt*64) * 256;
    const u16* lb = Hlo + ((size_t)b*Nn + nt*64) * 256;
    #pragma unroll
    for (int j = 0; j < 8; ++j){
      int id = t + j*256;
      int r = id >> 5, ch = id & 31;
      int sw = (ch ^ (r & 15)) * 8;
      *(uint4*)(Lh + r*256 + sw) = *(const uint4*)(hb + (size_t)r*256 + ch*8);
      *(uint4*)(Ll + r*256 + sw) = *(const uint4*)(lb + (size_t)r*256 + ch*8);
    }
  }
  __syncthreads();

  const float* Bs[3] = {bq, bk, bv};
  const float* Dsr[3] = {dq, dk, dv};
  const float* Zs[3] = {zq, zk, zv};

  #pragma unroll
  for (int ws = 0; ws < 3; ++ws){
    bf16x8 awh[8], awl[8];
    {
      const u16* wbh = WH + (size_t)ws*65536 + (size_t)(o0 + lo16) * 256 + quad*8;
      const u16* wbl = WL + (size_t)ws*65536 + (size_t)(o0 + lo16) * 256 + quad*8;
      #pragma unroll
      for (int k = 0; k < 8; ++k){
        awh[k] = *(const bf16x8*)(wbh + k*32);
        awl[k] = *(const bf16x8*)(wbl + k*32);
      }
    }
    f32x4 zf = {0.f,0.f,0.f,0.f};
    f32x4 acc[4] = {zf, zf, zf, zf};
    #pragma unroll
    for (int k = 0; k < 8; ++k){
      #pragma unroll
      for (int ns = 0; ns < 4; ++ns){
        int r = ns*16 + lo16;
        int ph = ((k*4 + quad) ^ (r & 15)) * 8;
        bf16x8 bh = *(const bf16x8*)(Lh + r*256 + ph);
        bf16x8 bl = *(const bf16x8*)(Ll + r*256 + ph);
        acc[ns] = MFMA16(awh[k], bh, acc[ns]);
        acc[ns] = MFMA16(awl[k], bh, acc[ns]);
        acc[ns] = MFMA16(awh[k], bl, acc[ns]);
      }
    }
    float bia[4];
    #pragma unroll
    for (int r = 0; r < 4; ++r) bia[r] = Bs[ws][o0 + quad*4 + r];
    float z = Zs[ws][0]; float invd = 1.0f / Dsr[ws][0];

    if (ws < 2){
      u8* outT = (ws == 0) ? qT8 : kT8;
      #pragma unroll
      for (int ns = 0; ns < 4; ++ns){
        int n = nt*64 + ns*16 + lo16;
        u32 w = 0;
        #pragma unroll
        for (int r = 0; r < 4; ++r){
          float v = acc[ns][r] + bia[r];
          float xq = fminf(fmaxf(rintf(v*invd) + z, 0.f), 255.f);
          int qi = (int)rintf(xq - z);
          w |= ((u32)(qi & 255)) << (8*r);
        }
        *(u32*)(outT + ((size_t)b*Nn + n)*Cc + o0 + quad*4) = w;
      }
    } else {
      #pragma unroll
      for (int ns = 0; ns < 4; ++ns){
        int n = nt*64 + ns*16 + lo16;
        #pragma unroll
        for (int r = 0; r < 4; ++r){
          float v = acc[ns][r] + bia[r];
          float xq = fminf(fmaxf(rintf(v*invd) + z, 0.f), 255.f);
          int qi = (int)rintf(xq - z);
          v8[((size_t)b*Cc + o0 + quad*4 + r)*Nn + n] = (u8)(qi & 255);
        }
      }
    }
  }
}

// ------------- proj conv + residual -> f32 out -------------
__global__ __launch_bounds__(256) void k_conv(const u16* __restrict__ WH, const u16* __restrict__ WL,
                                              const u16* __restrict__ Hh,
                                              const float* __restrict__ bias,
                                              const float* __restrict__ xres, float* __restrict__ outF){
  int nt = blockIdx.x, ot = blockIdx.y, b = blockIdx.z;
  __shared__ u16 Lh[64*128];
  int t = threadIdx.x, lane = t & 63, wave = t >> 6;
  int lo16 = lane & 15, quad = lane >> 4;
  int o0 = ot*64 + wave*16;

  bf16x8 awh[8], awl[8];
  {
    const u16* wbh = WH + (size_t)3*65536 + (size_t)(o0 + lo16) * 256 + quad*8;
    const u16* wbl = WL + (size_t)3*65536 + (size_t)(o0 + lo16) * 256 + quad*8;
    #pragma unroll
    for (int k = 0; k < 8; ++k){
      awh[k] = *(const bf16x8*)(wbh + k*32);
      awl[k] = *(const bf16x8*)(wbl + k*32);
    }
  }
  f32x4 zf = {0.f,0.f,0.f,0.f};
  f32x4 acc[4] = {zf, zf, zf, zf};

  const u16* hb = Hh + ((size_t)b*Nn + nt*64) * 256;
  for (int kc = 0; kc < 2; ++kc){
    __syncthreads();
    for (int id = t; id < 64*16; id += 256){
      int r = id >> 4, ch = id & 15;
      int sw = (ch ^ (r & 7)) * 8;
      *(uint4*)(Lh + r*128 + sw) = *(const uint4*)(hb + (size_t)r*256 + kc*128 + ch*8);
    }
    __syncthreads();
    #pragma unroll
    for (int k4 = 0; k4 < 4; ++k4){
      int k = kc*4 + k4;
      #pragma unroll
      for (int ns = 0; ns < 4; ++ns){
        int r = ns*16 + lo16;
        int ch = ((k4*4 + quad) ^ (r & 7)) * 8;
        bf16x8 bh = *(const bf16x8*)(Lh + r*128 + ch);
        acc[ns] = MFMA16(awh[k], bh, acc[ns]);
        acc[ns] = MFMA16(awl[k], bh, acc[ns]);
      }
    }
  }

  float bia[4];
  #pragma unroll
  for (int r = 0; r < 4; ++r) bia[r] = bias[o0 + quad*4 + r];
  #pragma unroll
  for (int ns = 0; ns < 4; ++ns){
    int n = nt*64 + ns*16 + lo16;
    #pragma unroll
    for (int r = 0; r < 4; ++r){
      size_t a = ((size_t)b*Cc + o0 + quad*4 + r)*Nn + n;
      outF[a] = xres[a] + acc[ns][r] + bia[r];
    }
  }
}

// ------------- merged: row norm^2 max + vsum -------------
static __device__ __forceinline__ int sq4(u32 w){
  int s = 0;
  #pragma unroll
  for (int j = 0; j < 4; ++j){ int v = (int)((signed char)((w >> (8*j)) & 0xffu)); s += v*v; }
  return s;
}
static __device__ __forceinline__ int ssum4(u32 w){
  return ((int)(w << 24) >> 24) + ((int)(w << 16) >> 24) + ((int)(w << 8) >> 24) + ((int)w >> 24);
}
__global__ __launch_bounds__(256) void k_normvs(const u8* __restrict__ qT8, const u8* __restrict__ kT8,
                                                const u8* __restrict__ v8,
                                                u32* __restrict__ stat, int* __restrict__ vsum){
  if (blockIdx.x < 128){
    int gid = blockIdx.x*256 + threadIdx.x;
    int which = gid >> 14;
    int rid = gid & 16383;
    const u8* row = (which ? kT8 : qT8) + (size_t)rid * 256;
    u32 acc = 0;
    const uint4* p = (const uint4*)row;
    #pragma unroll
    for (int i = 0; i < 16; ++i){
      uint4 w = p[i];
      acc += (u32)(sq4(w.x) + sq4(w.y) + sq4(w.z) + sq4(w.w));
    }
    #pragma unroll
    for (int msk = 32; msk > 0; msk >>= 1){
      u32 o = (u32)__shfl_xor((int)acc, msk, 64);
      acc = acc > o ? acc : o;
    }
    if ((threadIdx.x & 63) == 0)
      atomicMax(&stat[which*4 + (rid >> 12)], acc);
  } else {
    int row = blockIdx.x - 128;
    uint4 w = *(const uint4*)(v8 + (size_t)row*Nn + threadIdx.x*16);
    int s = ssum4(w.x) + ssum4(w.y) + ssum4(w.z) + ssum4(w.w);
    #pragma unroll
    for (int msk = 1; msk < 64; msk <<= 1) s += __shfl_xor(s, msk, 64);
    __shared__ int r4[4];
    if ((threadIdx.x & 63) == 0) r4[threadIdx.x >> 6] = s;
    __syncthreads();
    if (threadIdx.x == 0) vsum[row] = r4[0] + r4[1] + r4[2] + r4[3];
  }
}

// ------------- fused attention: 1024 thr (16 waves), 64 q-rows per block.
// Kt double-buffered; V direct from global; Pt double-buffered; 2-deep
// pipeline. Round 15: strength-reduced pointers + (mt&1) buffer selection
// + unroll 2 to cut pipeline-bookkeeping VALU. -------------
__global__ __launch_bounds__(1024) void k_qpv(const u8* __restrict__ qT8, const u8* __restrict__ kT8,
                                              const u8* __restrict__ v8,
                                              const u32* __restrict__ stat,
                                              const float* __restrict__ pdq, const float* __restrict__ pdk,
                                              const float* __restrict__ pdw, const float* __restrict__ pzw,
                                              const int* __restrict__ vsum,
                                              const float* __restrict__ pdv,
                                              u16* __restrict__ h2){
  int nt = blockIdx.x, b = blockIdx.y;
  __shared__ alignas(16) u8  Kt[2][64*256];   // K tile [m][c], swizzled
  __shared__ alignas(16) u32 Pt[2][64*16];    // P tile [n][16 dw], B-frag ready
  __shared__ float Lbuf[4][4][16];
  int t = threadIdx.x, lane = t & 63, w = t >> 6;
  int lo16 = lane & 15, q = lane >> 4;
  int ms = w & 3, nsq = w >> 2;

  float sc2 = pdq[0]*pdk[0]*0.0625f*LOG2E;
  float M2 = sc2 * sqrtf((float)stat[b] * (float)stat[4+b]);
  float zw = pzw[0];

  // Q B-fragments: rows n = nt*64 + nsq*16 + lo16
  i32x4 qf[4];
  {
    const u8* qb = qT8 + ((size_t)b*Nn + nt*64 + nsq*16 + lo16)*256;
    #pragma unroll
    for (int kk = 0; kk < 4; ++kk)
      qf[kk] = *(const i32x4*)(qb + kk*64 + q*16);
  }

  // K staging (1024 thr: 1 uint4 each)
  int krow = t >> 4, kch = t & 15;
  int kdst = krow*256 + ((kch ^ (krow & 15)) << 4);
  const u8* kb = kT8 + (size_t)b*Nn*256;

  int mrow = ms*16 + lo16;
  int kofs[4];
  #pragma unroll
  for (int kk = 0; kk < 4; ++kk) kofs[kk] = mrow*256 + (((kk*4 + q) ^ (mrow & 15)) << 4);

  // V direct: channel crv = w*16 + lo16 (16 waves cover 256 channels)
  const u8* vp = v8 + ((size_t)(b*Cc + w*16 + lo16))*Nn + q*16;

  // ---- pass 1: L(n) ----
  float lr = 0.f;
  {
    const u8* kld = kb + (size_t)krow*256 + kch*16;
    uint4 kr = *(const uint4*)(kld);                                   // tile 0
    *(uint4*)(Kt[0] + kdst) = kr;
    kr = *(const uint4*)(kld + 16384);                                 // tile 1
    kld += 2*16384;
    __syncthreads();
    i32x4 spA, spB;
    #pragma unroll 2
    for (int mt = 0; mt < 64; ++mt){
      int cur = mt & 1;
      i32x4 sA = {0,0,0,0}, sB = {0,0,0,0};
      sA = MFMA_I8(*(const i32x4*)(Kt[cur] + kofs[0]), qf[0], sA);
      sB = MFMA_I8(*(const i32x4*)(Kt[cur] + kofs[1]), qf[1], sB);
      sA = MFMA_I8(*(const i32x4*)(Kt[cur] + kofs[2]), qf[2], sA);
      sB = MFMA_I8(*(const i32x4*)(Kt[cur] + kofs[3]), qf[3], sB);
      if (mt < 63){
        *(uint4*)(Kt[cur ^ 1] + kdst) = kr;                            // stage mt+1
        if (mt < 62){ kr = *(const uint4*)(kld); kld += 16384; }
      }
      if (mt > 0){
        #pragma unroll
        for (int r = 0; r < 4; ++r)
          lr += EXP2F(fmaf((float)(spA[r] + spB[r]), sc2, -M2));       // tile mt-1
      }
      spA = sA; spB = sB;
      __syncthreads();
    }
    #pragma unroll
    for (int r = 0; r < 4; ++r)
      lr += EXP2F(fmaf((float)(spA[r] + spB[r]), sc2, -M2));           // tile 63
  }
  lr += __shfl_xor(lr, 16, 64);
  lr += __shfl_xor(lr, 32, 64);
  if (lane < 16) Lbuf[nsq][ms][lo16] = lr;
  __syncthreads();
  float Ls = Lbuf[nsq][0][lo16] + Lbuf[nsq][1][lo16] + Lbuf[nsq][2][lo16] + Lbuf[nsq][3][lo16];
  float crn = __log2f(1.0f / (pdw[0] * Ls)) - M2;

  // ---- pass 2: 2-deep pipeline ----
  i32x4 zi = {0,0,0,0};
  i32x4 acc[4] = {zi,zi,zi,zi};
  int nrow = nsq*16 + lo16;
  int pdst = nrow*16 + ((ms ^ (nrow & 3) ^ ((nrow >> 2) & 3)) << 2) + q;
  int pofs[4];
  #pragma unroll
  for (int ns = 0; ns < 4; ++ns){
    int pr = ns*16 + lo16;
    pofs[ns] = pr*16 + ((q ^ (pr & 3) ^ ((pr >> 2) & 3)) << 2);
  }
  {
    const u8* kld = kb + (size_t)krow*256 + kch*16;
    uint4 kr = *(const uint4*)(kld);                                   // tile 0
    *(uint4*)(Kt[0] + kdst) = kr;
    kr = *(const uint4*)(kld + 16384);                                 // tile 1
    kld += 2*16384;
    const u8* vld = vp + 64;                                           // V tile 1
    i32x4 af = *(const i32x4*)(vp);                                    // V tile 0
    i32x4 af_p, af_pp;
    i32x4 spA, spB;
    __syncthreads();
    #pragma unroll 2
    for (int mt = 0; mt < 64; ++mt){
      int cur = mt & 1;
      // QK(mt): result consumed at iter mt+1
      i32x4 sA = {0,0,0,0}, sB = {0,0,0,0};
      sA = MFMA_I8(*(const i32x4*)(Kt[cur] + kofs[0]), qf[0], sA);
      sB = MFMA_I8(*(const i32x4*)(Kt[cur] + kofs[1]), qf[1], sB);
      sA = MFMA_I8(*(const i32x4*)(Kt[cur] + kofs[2]), qf[2], sA);
      sB = MFMA_I8(*(const i32x4*)(Kt[cur] + kofs[3]), qf[3], sB);
      // stage K(mt+1)
      if (mt < 63){
        *(uint4*)(Kt[cur ^ 1] + kdst) = kr;
        if (mt < 62){ kr = *(const uint4*)(kld); kld += 16384; }
      }
      // PV(mt-2): Pt[cur] (written at iter mt-1, pre-barrier), af_pp
      if (mt > 1){
        acc[0] = MFMA_I8(af_pp, *(const i32x4*)(Pt[cur] + pofs[0]), acc[0]);
        acc[1] = MFMA_I8(af_pp, *(const i32x4*)(Pt[cur] + pofs[1]), acc[1]);
        acc[2] = MFMA_I8(af_pp, *(const i32x4*)(Pt[cur] + pofs[2]), acc[2]);
        acc[3] = MFMA_I8(af_pp, *(const i32x4*)(Pt[cur] + pofs[3]), acc[3]);
      }
      // quant s(mt-1) -> Pt[cur^1]  (registers ready since last iter)
      if (mt > 0){
        u32 wp = 0;
        #pragma unroll
        for (int r = 0; r < 4; ++r){
          float at = EXP2F(fmaf((float)(spA[r] + spB[r]), sc2, crn));
          float y = fminf(fmaxf(rintf(at) + zw, 0.f), 255.f);
          wp = __builtin_amdgcn_cvt_pk_u8_f32(y, (u32)r, wp);
        }
        Pt[cur ^ 1][pdst] = wp ^ 0x80808080u;
      }
      // rotate (absorbed by unroll-2 register renaming)
      spA = sA; spB = sB;
      af_pp = af_p; af_p = af;
      if (mt < 63){ af = *(const i32x4*)(vld); vld += 64; }
      __syncthreads();
    }
    // tail: PV(62) reads Pt[0] (written iter 63); quant(63) -> Pt[1]
    acc[0] = MFMA_I8(af_pp, *(const i32x4*)(Pt[0] + pofs[0]), acc[0]);
    acc[1] = MFMA_I8(af_pp, *(const i32x4*)(Pt[0] + pofs[1]), acc[1]);
    acc[2] = MFMA_I8(af_pp, *(const i32x4*)(Pt[0] + pofs[2]), acc[2]);
    acc[3] = MFMA_I8(af_pp, *(const i32x4*)(Pt[0] + pofs[3]), acc[3]);
    {
      u32 wp = 0;
      #pragma unroll
      for (int r = 0; r < 4; ++r){
        float at = EXP2F(fmaf((float)(spA[r] + spB[r]), sc2, crn));
        float y = fminf(fmaxf(rintf(at) + zw, 0.f), 255.f);
        wp = __builtin_amdgcn_cvt_pk_u8_f32(y, (u32)r, wp);
      }
      Pt[1][pdst] = wp ^ 0x80808080u;
    }
    __syncthreads();
    acc[0] = MFMA_I8(af_p, *(const i32x4*)(Pt[1] + pofs[0]), acc[0]);
    acc[1] = MFMA_I8(af_p, *(const i32x4*)(Pt[1] + pofs[1]), acc[1]);
    acc[2] = MFMA_I8(af_p, *(const i32x4*)(Pt[1] + pofs[2]), acc[2]);
    acc[3] = MFMA_I8(af_p, *(const i32x4*)(Pt[1] + pofs[3]), acc[3]);
  }

  float s = pdv[0] * pdw[0];
  float corr = s * (128.0f - zw);
  int c0 = w*16 + q*4;
  float cv[4];
  #pragma unroll
  for (int r = 0; r < 4; ++r) cv[r] = corr * (float)vsum[b*Cc + c0 + r];
  #pragma unroll
  for (int ns = 0; ns < 4; ++ns){
    int n = nt*64 + ns*16 + lo16;
    U64c Uh;
    #pragma unroll
    for (int r = 0; r < 4; ++r)
      Uh.u[r] = f2bf(s*(float)acc[ns][r] + cv[r]);
    *(uint2*)(h2 + ((size_t)b*Nn + n)*Cc + c0) = Uh.v;
  }
}

extern "C" void kernel_launch(void* const* d_in, const int* in_sizes, int n_in,
                              void* d_out, int out_size, void* d_ws, size_t ws_size,
                              hipStream_t stream){
  (void)in_sizes; (void)n_in; (void)out_size; (void)ws_size;
  const float* x   = (const float*)d_in[0];
  const float* gsc = (const float*)d_in[1];
  const float* gbi = (const float*)d_in[2];
  const float* wq  = (const float*)d_in[3];
  const float* bq  = (const float*)d_in[4];
  const float* wk  = (const float*)d_in[5];
  const float* bk  = (const float*)d_in[6];
  const float* wv  = (const float*)d_in[7];
  const float* bv  = (const float*)d_in[8];
  const float* wp  = (const float*)d_in[9];
  const float* bp  = (const float*)d_in[10];
  const float* dq  = (const float*)d_in[11];
  const float* zq  = (const float*)d_in[12];
  const float* dk  = (const float*)d_in[13];
  const float* zk  = (const float*)d_in[14];
  const float* dv  = (const float*)d_in[15];
  const float* zv  = (const float*)d_in[16];
  const float* dw  = (const float*)d_in[17];
  const float* zw  = (const float*)d_in[18];
  float* out = (float*)d_out;

  const size_t SZT = (size_t)Bb*Nn*Cc;
  u16* hT_hi = (u16*)d_ws;
  u16* hT_lo = hT_hi + SZT;
  u16* h2    = hT_lo + SZT;
  u8*  qT8   = (u8*)(h2 + SZT);
  u8*  kT8   = qT8 + SZT;
  u8*  v8    = kT8 + SZT;
  u16* WH    = (u16*)(v8 + SZT);
  u16* WL    = WH + 4*65536;
  float* mu  = (float*)(WL + 4*65536);
  float* rs  = mu + 128;
  u32*  stat = (u32*)(rs + 128);
  int*  vsum = (int*)(stat + 8);

  k_gn_stats<<<dim3(Bb*NGRP), 256, 0, stream>>>(x, mu, rs);
  k_wsplit<<<dim3(1024), 256, 0, stream>>>(wq, wk, wv, wp, WH, WL);
  k_gn_apply<<<dim3(Nn/64, Cc/64, Bb), 256, 0, stream>>>(x, gsc, gbi, mu, rs, hT_hi, hT_lo);

  k_convqkv<<<dim3(Nn/64, 4, Bb), 256, 0, stream>>>(WH, WL, hT_hi, hT_lo,
                                                    bq, bk, bv, dq, zq, dk, zk, dv, zv,
                                                    qT8, kT8, v8);

  hipMemsetAsync(stat, 0, 8*sizeof(u32), stream);
  k_normvs<<<dim3(128 + Bb*Cc), 256, 0, stream>>>(qT8, kT8, v8, stat, vsum);

  k_qpv<<<dim3(Nn/64, Bb), 1024, 0, stream>>>(qT8, kT8, v8, stat, dq, dk, dw, zw, vsum, dv, h2);

  k_conv<<<dim3(Nn/64, 4, Bb), 256, 0, stream>>>(WH, WL, h2, bp, x, out);
}

// Round 8
// 246.185 us; speedup vs baseline: 1.0535x; 1.0535x over previous
//
#include <hip/hip_runtime.h>

// QuantAttnBlock on gfx950, round 16: k_qpv BK=128 -- two 64-row K tiles per
// barrier iteration. Barrier count halves (128 -> ~65); per-iter work doubles
// (8 QK MFMAs, 8 PV MFMAs, 8 quant values). LDS 81KB (1 block/CU anyway).
// Same 2-deep pipeline + hazard proofs as r15, per 128-row supertile.
// Numerics identical (verified absmax ~0.0234).

#define Bb 4
#define Cc 256
#define Nn 4096
#define NGRP 32
#define LOG2E 1.4426950408889634f

typedef unsigned short u16;
typedef unsigned int   u32;
typedef unsigned char  u8;
typedef __attribute__((ext_vector_type(8))) short bf16x8;
typedef __attribute__((ext_vector_type(4))) float f32x4;
typedef __attribute__((ext_vector_type(4))) int   i32x4;

#define MFMA16(a,b,c)    __builtin_amdgcn_mfma_f32_16x16x32_bf16((a),(b),(c),0,0,0)
#define MFMA_I8(a,b,c)   __builtin_amdgcn_mfma_i32_16x16x64_i8((a),(b),(c),0,0,0)
#define EXP2F(x)         __builtin_amdgcn_exp2f(x)

static __device__ __forceinline__ u16 f2bf(float x){
  u32 u = __float_as_uint(x);
  u += 0x7fffu + ((u >> 16) & 1u);
  return (u16)(u >> 16);
}
static __device__ __forceinline__ float bf2f(u16 h){ return __uint_as_float(((u32)h) << 16); }

union U64c { u16 u[4]; uint2 v; };

// ---------------- GroupNorm stats ----------------
__global__ __launch_bounds__(256) void k_gn_stats(const float* __restrict__ x,
                                                  float* __restrict__ mu, float* __restrict__ rs){
  int bg = blockIdx.x;
  const float4* p = (const float4*)(x + (size_t)bg * (8 * Nn));
  float s = 0.f, q = 0.f;
  for (int i = threadIdx.x; i < 8*Nn/4; i += 256){
    float4 v = p[i];
    s += v.x + v.y + v.z + v.w;
    q += v.x*v.x + v.y*v.y + v.z*v.z + v.w*v.w;
  }
  __shared__ float rsum[256], rsq[256];
  rsum[threadIdx.x] = s; rsq[threadIdx.x] = q;
  __syncthreads();
  for (int off = 128; off > 0; off >>= 1){
    if (threadIdx.x < off){ rsum[threadIdx.x] += rsum[threadIdx.x+off]; rsq[threadIdx.x] += rsq[threadIdx.x+off]; }
    __syncthreads();
  }
  if (threadIdx.x == 0){
    const float inv = 1.0f / (8*Nn);
    float m = rsum[0]*inv;
    float var = rsq[0]*inv - m*m;
    mu[bg] = m; rs[bg] = rsqrtf(var + 1e-6f);
  }
}

// ------------- weight split: 4 matrices f32 -> hi/lo bf16 -------------
__global__ __launch_bounds__(256) void k_wsplit(const float* __restrict__ wq, const float* __restrict__ wk,
                                                const float* __restrict__ wv, const float* __restrict__ wp,
                                                u16* __restrict__ WH, u16* __restrict__ WL){
  int gid = blockIdx.x*256 + threadIdx.x;
  int mat = gid >> 16, idx = gid & 65535;
  const float* src = (mat == 0) ? wq : (mat == 1) ? wk : (mat == 2) ? wv : wp;
  float w = src[idx];
  u16 h = f2bf(w);
  WH[gid] = h;
  WL[gid] = f2bf(w - bf2f(h));
}

// ------------- GroupNorm apply + transpose -> hT hi/lo [b][n][c] -------------
__global__ __launch_bounds__(256) void k_gn_apply(const float* __restrict__ x,
                                                  const float* __restrict__ gsc, const float* __restrict__ gbi,
                                                  const float* __restrict__ mu, const float* __restrict__ rs,
                                                  u16* __restrict__ hhi, u16* __restrict__ hlo){
  int nt = blockIdx.x, ct = blockIdx.y, b = blockIdx.z;
  int n0 = nt*64, c0 = ct*64;
  __shared__ float yt[64*65];
  __shared__ float sa[64], sb[64];
  int t = threadIdx.x;
  if (t < 64){
    int c = c0 + t;
    int bg = b*NGRP + (c >> 3);
    float a = rs[bg] * gsc[c];
    sa[t] = a;
    sb[t] = gbi[c] - mu[bg]*a;
  }
  __syncthreads();
  #pragma unroll
  for (int j = 0; j < 4; ++j){
    int id = t + j*256;
    int r = id >> 4, cq = id & 15;
    float4 v = *(const float4*)(x + ((size_t)b*Cc + c0 + r)*Nn + n0 + cq*4);
    float a = sa[r], bb = sb[r];
    yt[r*65 + cq*4 + 0] = v.x*a + bb;
    yt[r*65 + cq*4 + 1] = v.y*a + bb;
    yt[r*65 + cq*4 + 2] = v.z*a + bb;
    yt[r*65 + cq*4 + 3] = v.w*a + bb;
  }
  __syncthreads();
  int nl = t >> 2, cg = (t & 3) * 16;
  size_t base = ((size_t)b*Nn + n0 + nl)*Cc + c0 + cg;
  #pragma unroll
  for (int half = 0; half < 2; ++half){
    union { u16 u[8]; uint4 v; } Ph, Pl;
    #pragma unroll
    for (int u = 0; u < 8; ++u){
      float y = yt[(cg + half*8 + u)*65 + nl];
      u16 h = f2bf(y);
      Ph.u[u] = h; Pl.u[u] = f2bf(y - bf2f(h));
    }
    *(uint4*)(hhi + base + half*8) = Ph.v;
    *(uint4*)(hlo + base + half*8) = Pl.v;
  }
}

// ------------- Fused QKV conv GEMM (bf16 hi/lo, ~fp32 accurate) -------------
__global__ __launch_bounds__(256) void k_convqkv(const u16* __restrict__ WH, const u16* __restrict__ WL,
                                                 const u16* __restrict__ Hhi, const u16* __restrict__ Hlo,
                                                 const float* __restrict__ bq, const float* __restrict__ bk,
                                                 const float* __restrict__ bv,
                                                 const float* __restrict__ dq, const float* __restrict__ zq,
                                                 const float* __restrict__ dk, const float* __restrict__ zk,
                                                 const float* __restrict__ dv, const float* __restrict__ zv,
                                                 u8* __restrict__ qT8, u8* __restrict__ kT8,
                                                 u8* __restrict__ v8){
  int nt = blockIdx.x, ot = blockIdx.y, b = blockIdx.z;
  __shared__ u16 Lh[64*256], Ll[64*256];
  int t = threadIdx.x, lane = t & 63, wave = t >> 6;
  int lo16 = lane & 15, quad = lane >> 4;
  int o0 = ot*64 + wave*16;

  {
    const u16* hb = Hhi + ((size_t)b*Nn + nt*64) * 256;
    const u16* lb = Hlo + ((size_t)b*Nn + nt*64) * 256;
    #pragma unroll
    for (int j = 0; j < 8; ++j){
      int id = t + j*256;
      int r = id >> 5, ch = id & 31;
      int sw = (ch ^ (r & 15)) * 8;
      *(uint4*)(Lh + r*256 + sw) = *(const uint4*)(hb + (size_t)r*256 + ch*8);
      *(uint4*)(Ll + r*256 + sw) = *(const uint4*)(lb + (size_t)r*256 + ch*8);
    }
  }
  __syncthreads();

  const float* Bs[3] = {bq, bk, bv};
  const float* Dsr[3] = {dq, dk, dv};
  const float* Zs[3] = {zq, zk, zv};

  #pragma unroll
  for (int ws = 0; ws < 3; ++ws){
    bf16x8 awh[8], awl[8];
    {
      const u16* wbh = WH + (size_t)ws*65536 + (size_t)(o0 + lo16) * 256 + quad*8;
      const u16* wbl = WL + (size_t)ws*65536 + (size_t)(o0 + lo16) * 256 + quad*8;
      #pragma unroll
      for (int k = 0; k < 8; ++k){
        awh[k] = *(const bf16x8*)(wbh + k*32);
        awl[k] = *(const bf16x8*)(wbl + k*32);
      }
    }
    f32x4 zf = {0.f,0.f,0.f,0.f};
    f32x4 acc[4] = {zf, zf, zf, zf};
    #pragma unroll
    for (int k = 0; k < 8; ++k){
      #pragma unroll
      for (int ns = 0; ns < 4; ++ns){
        int r = ns*16 + lo16;
        int ph = ((k*4 + quad) ^ (r & 15)) * 8;
        bf16x8 bh = *(const bf16x8*)(Lh + r*256 + ph);
        bf16x8 bl = *(const bf16x8*)(Ll + r*256 + ph);
        acc[ns] = MFMA16(awh[k], bh, acc[ns]);
        acc[ns] = MFMA16(awl[k], bh, acc[ns]);
        acc[ns] = MFMA16(awh[k], bl, acc[ns]);
      }
    }
    float bia[4];
    #pragma unroll
    for (int r = 0; r < 4; ++r) bia[r] = Bs[ws][o0 + quad*4 + r];
    float z = Zs[ws][0]; float invd = 1.0f / Dsr[ws][0];

    if (ws < 2){
      u8* outT = (ws == 0) ? qT8 : kT8;
      #pragma unroll
      for (int ns = 0; ns < 4; ++ns){
        int n = nt*64 + ns*16 + lo16;
        u32 w = 0;
        #pragma unroll
        for (int r = 0; r < 4; ++r){
          float v = acc[ns][r] + bia[r];
          float xq = fminf(fmaxf(rintf(v*invd) + z, 0.f), 255.f);
          int qi = (int)rintf(xq - z);
          w |= ((u32)(qi & 255)) << (8*r);
        }
        *(u32*)(outT + ((size_t)b*Nn + n)*Cc + o0 + quad*4) = w;
      }
    } else {
      #pragma unroll
      for (int ns = 0; ns < 4; ++ns){
        int n = nt*64 + ns*16 + lo16;
        #pragma unroll
        for (int r = 0; r < 4; ++r){
          float v = acc[ns][r] + bia[r];
          float xq = fminf(fmaxf(rintf(v*invd) + z, 0.f), 255.f);
          int qi = (int)rintf(xq - z);
          v8[((size_t)b*Cc + o0 + quad*4 + r)*Nn + n] = (u8)(qi & 255);
        }
      }
    }
  }
}

// ------------- proj conv + residual -> f32 out -------------
__global__ __launch_bounds__(256) void k_conv(const u16* __restrict__ WH, const u16* __restrict__ WL,
                                              const u16* __restrict__ Hh,
                                              const float* __restrict__ bias,
                                              const float* __restrict__ xres, float* __restrict__ outF){
  int nt = blockIdx.x, ot = blockIdx.y, b = blockIdx.z;
  __shared__ u16 Lh[64*128];
  int t = threadIdx.x, lane = t & 63, wave = t >> 6;
  int lo16 = lane & 15, quad = lane >> 4;
  int o0 = ot*64 + wave*16;

  bf16x8 awh[8], awl[8];
  {
    const u16* wbh = WH + (size_t)3*65536 + (size_t)(o0 + lo16) * 256 + quad*8;
    const u16* wbl = WL + (size_t)3*65536 + (size_t)(o0 + lo16) * 256 + quad*8;
    #pragma unroll
    for (int k = 0; k < 8; ++k){
      awh[k] = *(const bf16x8*)(wbh + k*32);
      awl[k] = *(const bf16x8*)(wbl + k*32);
    }
  }
  f32x4 zf = {0.f,0.f,0.f,0.f};
  f32x4 acc[4] = {zf, zf, zf, zf};

  const u16* hb = Hh + ((size_t)b*Nn + nt*64) * 256;
  for (int kc = 0; kc < 2; ++kc){
    __syncthreads();
    for (int id = t; id < 64*16; id += 256){
      int r = id >> 4, ch = id & 15;
      int sw = (ch ^ (r & 7)) * 8;
      *(uint4*)(Lh + r*128 + sw) = *(const uint4*)(hb + (size_t)r*256 + kc*128 + ch*8);
    }
    __syncthreads();
    #pragma unroll
    for (int k4 = 0; k4 < 4; ++k4){
      int k = kc*4 + k4;
      #pragma unroll
      for (int ns = 0; ns < 4; ++ns){
        int r = ns*16 + lo16;
        int ch = ((k4*4 + quad) ^ (r & 7)) * 8;
        bf16x8 bh = *(const bf16x8*)(Lh + r*128 + ch);
        acc[ns] = MFMA16(awh[k], bh, acc[ns]);
        acc[ns] = MFMA16(awl[k], bh, acc[ns]);
      }
    }
  }

  float bia[4];
  #pragma unroll
  for (int r = 0; r < 4; ++r) bia[r] = bias[o0 + quad*4 + r];
  #pragma unroll
  for (int ns = 0; ns < 4; ++ns){
    int n = nt*64 + ns*16 + lo16;
    #pragma unroll
    for (int r = 0; r < 4; ++r){
      size_t a = ((size_t)b*Cc + o0 + quad*4 + r)*Nn + n;
      outF[a] = xres[a] + acc[ns][r] + bia[r];
    }
  }
}

// ------------- merged: row norm^2 max + vsum -------------
static __device__ __forceinline__ int sq4(u32 w){
  int s = 0;
  #pragma unroll
  for (int j = 0; j < 4; ++j){ int v = (int)((signed char)((w >> (8*j)) & 0xffu)); s += v*v; }
  return s;
}
static __device__ __forceinline__ int ssum4(u32 w){
  return ((int)(w << 24) >> 24) + ((int)(w << 16) >> 24) + ((int)(w << 8) >> 24) + ((int)w >> 24);
}
__global__ __launch_bounds__(256) void k_normvs(const u8* __restrict__ qT8, const u8* __restrict__ kT8,
                                                const u8* __restrict__ v8,
                                                u32* __restrict__ stat, int* __restrict__ vsum){
  if (blockIdx.x < 128){
    int gid = blockIdx.x*256 + threadIdx.x;
    int which = gid >> 14;
    int rid = gid & 16383;
    const u8* row = (which ? kT8 : qT8) + (size_t)rid * 256;
    u32 acc = 0;
    const uint4* p = (const uint4*)row;
    #pragma unroll
    for (int i = 0; i < 16; ++i){
      uint4 w = p[i];
      acc += (u32)(sq4(w.x) + sq4(w.y) + sq4(w.z) + sq4(w.w));
    }
    #pragma unroll
    for (int msk = 32; msk > 0; msk >>= 1){
      u32 o = (u32)__shfl_xor((int)acc, msk, 64);
      acc = acc > o ? acc : o;
    }
    if ((threadIdx.x & 63) == 0)
      atomicMax(&stat[which*4 + (rid >> 12)], acc);
  } else {
    int row = blockIdx.x - 128;
    uint4 w = *(const uint4*)(v8 + (size_t)row*Nn + threadIdx.x*16);
    int s = ssum4(w.x) + ssum4(w.y) + ssum4(w.z) + ssum4(w.w);
    #pragma unroll
    for (int msk = 1; msk < 64; msk <<= 1) s += __shfl_xor(s, msk, 64);
    __shared__ int r4[4];
    if ((threadIdx.x & 63) == 0) r4[threadIdx.x >> 6] = s;
    __syncthreads();
    if (threadIdx.x == 0) vsum[row] = r4[0] + r4[1] + r4[2] + r4[3];
  }
}

// ------------- fused attention: 1024 thr (16 waves), 64 q-rows per block.
// BK=128: each barrier iteration handles TWO 64-row K tiles. Kt[2][2] (64KB),
// Pt[2][2] (16KB), V direct from global, 2-deep pipeline per supertile:
// iter i = { QK(2i,2i+1), stage K pair i+1, PV(pair i-2), quant(pair i-1),
// barrier }. Hazards: same proofs as r15 at supertile granularity. -------------
__global__ __launch_bounds__(1024) void k_qpv(const u8* __restrict__ qT8, const u8* __restrict__ kT8,
                                              const u8* __restrict__ v8,
                                              const u32* __restrict__ stat,
                                              const float* __restrict__ pdq, const float* __restrict__ pdk,
                                              const float* __restrict__ pdw, const float* __restrict__ pzw,
                                              const int* __restrict__ vsum,
                                              const float* __restrict__ pdv,
                                              u16* __restrict__ h2){
  int nt = blockIdx.x, b = blockIdx.y;
  __shared__ alignas(16) u8  Kt[2][2][64*256];  // [iter-parity][tile-in-pair]
  __shared__ alignas(16) u32 Pt[2][2][64*16];   // [iter-parity][tile-in-pair]
  __shared__ float Lbuf[4][4][16];
  int t = threadIdx.x, lane = t & 63, w = t >> 6;
  int lo16 = lane & 15, q = lane >> 4;
  int ms = w & 3, nsq = w >> 2;

  float sc2 = pdq[0]*pdk[0]*0.0625f*LOG2E;
  float M2 = sc2 * sqrtf((float)stat[b] * (float)stat[4+b]);
  float zw = pzw[0];

  // Q B-fragments: rows n = nt*64 + nsq*16 + lo16
  i32x4 qf[4];
  {
    const u8* qb = qT8 + ((size_t)b*Nn + nt*64 + nsq*16 + lo16)*256;
    #pragma unroll
    for (int kk = 0; kk < 4; ++kk)
      qf[kk] = *(const i32x4*)(qb + kk*64 + q*16);
  }

  // K staging (1024 thr: 1 uint4 per tile, 2 tiles per iter)
  int krow = t >> 4, kch = t & 15;
  int kdst = krow*256 + ((kch ^ (krow & 15)) << 4);
  const u8* kb = kT8 + (size_t)b*Nn*256;

  int mrow = ms*16 + lo16;
  int kofs[4];
  #pragma unroll
  for (int kk = 0; kk < 4; ++kk) kofs[kk] = mrow*256 + (((kk*4 + q) ^ (mrow & 15)) << 4);

  // V direct: channel = w*16 + lo16 (16 waves cover 256 channels)
  const u8* vp = v8 + ((size_t)(b*Cc + w*16 + lo16))*Nn + q*16;

  // ---- pass 1: L(n) ----
  float lr = 0.f;
  {
    const u8* kld = kb + (size_t)krow*256 + kch*16;
    uint4 kr0 = *(const uint4*)(kld);
    uint4 kr1 = *(const uint4*)(kld + 16384);
    *(uint4*)(Kt[0][0] + kdst) = kr0;
    *(uint4*)(Kt[0][1] + kdst) = kr1;
    kld += 2*16384;
    kr0 = *(const uint4*)(kld);
    kr1 = *(const uint4*)(kld + 16384);
    kld += 2*16384;
    __syncthreads();
    i32x4 spA0, spB0, spA1, spB1;
    #pragma unroll 2
    for (int i = 0; i < 32; ++i){
      int cur = i & 1;
      i32x4 sA0 = {0,0,0,0}, sB0 = {0,0,0,0}, sA1 = {0,0,0,0}, sB1 = {0,0,0,0};
      sA0 = MFMA_I8(*(const i32x4*)(Kt[cur][0] + kofs[0]), qf[0], sA0);
      sB0 = MFMA_I8(*(const i32x4*)(Kt[cur][0] + kofs[1]), qf[1], sB0);
      sA1 = MFMA_I8(*(const i32x4*)(Kt[cur][1] + kofs[0]), qf[0], sA1);
      sB1 = MFMA_I8(*(const i32x4*)(Kt[cur][1] + kofs[1]), qf[1], sB1);
      sA0 = MFMA_I8(*(const i32x4*)(Kt[cur][0] + kofs[2]), qf[2], sA0);
      sB0 = MFMA_I8(*(const i32x4*)(Kt[cur][0] + kofs[3]), qf[3], sB0);
      sA1 = MFMA_I8(*(const i32x4*)(Kt[cur][1] + kofs[2]), qf[2], sA1);
      sB1 = MFMA_I8(*(const i32x4*)(Kt[cur][1] + kofs[3]), qf[3], sB1);
      if (i < 31){
        *(uint4*)(Kt[cur ^ 1][0] + kdst) = kr0;
        *(uint4*)(Kt[cur ^ 1][1] + kdst) = kr1;
        if (i < 30){
          kr0 = *(const uint4*)(kld);
          kr1 = *(const uint4*)(kld + 16384);
          kld += 2*16384;
        }
      }
      if (i > 0){
        #pragma unroll
        for (int r = 0; r < 4; ++r){
          lr += EXP2F(fmaf((float)(spA0[r] + spB0[r]), sc2, -M2));
          lr += EXP2F(fmaf((float)(spA1[r] + spB1[r]), sc2, -M2));
        }
      }
      spA0 = sA0; spB0 = sB0; spA1 = sA1; spB1 = sB1;
      __syncthreads();
    }
    #pragma unroll
    for (int r = 0; r < 4; ++r){
      lr += EXP2F(fmaf((float)(spA0[r] + spB0[r]), sc2, -M2));
      lr += EXP2F(fmaf((float)(spA1[r] + spB1[r]), sc2, -M2));
    }
  }
  lr += __shfl_xor(lr, 16, 64);
  lr += __shfl_xor(lr, 32, 64);
  if (lane < 16) Lbuf[nsq][ms][lo16] = lr;
  __syncthreads();
  float Ls = Lbuf[nsq][0][lo16] + Lbuf[nsq][1][lo16] + Lbuf[nsq][2][lo16] + Lbuf[nsq][3][lo16];
  float crn = __log2f(1.0f / (pdw[0] * Ls)) - M2;

  // ---- pass 2: 2-deep pipeline over supertiles ----
  i32x4 zi = {0,0,0,0};
  i32x4 acc[4] = {zi,zi,zi,zi};
  int nrow = nsq*16 + lo16;
  int pdst = nrow*16 + ((ms ^ (nrow & 3) ^ ((nrow >> 2) & 3)) << 2) + q;
  int pofs[4];
  #pragma unroll
  for (int ns = 0; ns < 4; ++ns){
    int pr = ns*16 + lo16;
    pofs[ns] = pr*16 + ((q ^ (pr & 3) ^ ((pr >> 2) & 3)) << 2);
  }
  {
    const u8* kld = kb + (size_t)krow*256 + kch*16;
    uint4 kr0 = *(const uint4*)(kld);
    uint4 kr1 = *(const uint4*)(kld + 16384);
    *(uint4*)(Kt[0][0] + kdst) = kr0;
    *(uint4*)(Kt[0][1] + kdst) = kr1;
    kld += 2*16384;
    kr0 = *(const uint4*)(kld);
    kr1 = *(const uint4*)(kld + 16384);
    kld += 2*16384;
    const u8* vld = vp + 128;
    i32x4 af0 = *(const i32x4*)(vp);          // V tile 0
    i32x4 af1 = *(const i32x4*)(vp + 64);     // V tile 1
    i32x4 af0p, af1p, af0pp, af1pp;
    i32x4 spA0, spB0, spA1, spB1;
    __syncthreads();
    #pragma unroll 2
    for (int i = 0; i < 32; ++i){
      int cur = i & 1;
      // QK(pair i): consumed at iter i+1
      i32x4 sA0 = {0,0,0,0}, sB0 = {0,0,0,0}, sA1 = {0,0,0,0}, sB1 = {0,0,0,0};
      sA0 = MFMA_I8(*(const i32x4*)(Kt[cur][0] + kofs[0]), qf[0], sA0);
      sB0 = MFMA_I8(*(const i32x4*)(Kt[cur][0] + kofs[1]), qf[1], sB0);
      sA1 = MFMA_I8(*(const i32x4*)(Kt[cur][1] + kofs[0]), qf[0], sA1);
      sB1 = MFMA_I8(*(const i32x4*)(Kt[cur][1] + kofs[1]), qf[1], sB1);
      sA0 = MFMA_I8(*(const i32x4*)(Kt[cur][0] + kofs[2]), qf[2], sA0);
      sB0 = MFMA_I8(*(const i32x4*)(Kt[cur][0] + kofs[3]), qf[3], sB0);
      sA1 = MFMA_I8(*(const i32x4*)(Kt[cur][1] + kofs[2]), qf[2], sA1);
      sB1 = MFMA_I8(*(const i32x4*)(Kt[cur][1] + kofs[3]), qf[3], sB1);
      // stage K(pair i+1)
      if (i < 31){
        *(uint4*)(Kt[cur ^ 1][0] + kdst) = kr0;
        *(uint4*)(Kt[cur ^ 1][1] + kdst) = kr1;
        if (i < 30){
          kr0 = *(const uint4*)(kld);
          kr1 = *(const uint4*)(kld + 16384);
          kld += 2*16384;
        }
      }
      // PV(pair i-2): Pt[cur] (written at iter i-1, pre-barrier), af*pp
      if (i > 1){
        acc[0] = MFMA_I8(af0pp, *(const i32x4*)(Pt[cur][0] + pofs[0]), acc[0]);
        acc[1] = MFMA_I8(af0pp, *(const i32x4*)(Pt[cur][0] + pofs[1]), acc[1]);
        acc[2] = MFMA_I8(af0pp, *(const i32x4*)(Pt[cur][0] + pofs[2]), acc[2]);
        acc[3] = MFMA_I8(af0pp, *(const i32x4*)(Pt[cur][0] + pofs[3]), acc[3]);
        acc[0] = MFMA_I8(af1pp, *(const i32x4*)(Pt[cur][1] + pofs[0]), acc[0]);
        acc[1] = MFMA_I8(af1pp, *(const i32x4*)(Pt[cur][1] + pofs[1]), acc[1]);
        acc[2] = MFMA_I8(af1pp, *(const i32x4*)(Pt[cur][1] + pofs[2]), acc[2]);
        acc[3] = MFMA_I8(af1pp, *(const i32x4*)(Pt[cur][1] + pofs[3]), acc[3]);
      }
      // quant(pair i-1) -> Pt[cur^1][0/1]
      if (i > 0){
        u32 wp0 = 0, wp1 = 0;
        #pragma unroll
        for (int r = 0; r < 4; ++r){
          float at0 = EXP2F(fmaf((float)(spA0[r] + spB0[r]), sc2, crn));
          float y0 = fminf(fmaxf(rintf(at0) + zw, 0.f), 255.f);
          wp0 = __builtin_amdgcn_cvt_pk_u8_f32(y0, (u32)r, wp0);
          float at1 = EXP2F(fmaf((float)(spA1[r] + spB1[r]), sc2, crn));
          float y1 = fminf(fmaxf(rintf(at1) + zw, 0.f), 255.f);
          wp1 = __builtin_amdgcn_cvt_pk_u8_f32(y1, (u32)r, wp1);
        }
        Pt[cur ^ 1][0][pdst] = wp0 ^ 0x80808080u;
        Pt[cur ^ 1][1][pdst] = wp1 ^ 0x80808080u;
      }
      // rotate
      spA0 = sA0; spB0 = sB0; spA1 = sA1; spB1 = sB1;
      af0pp = af0p; af0p = af0; af1pp = af1p; af1p = af1;
      if (i < 31){
        af0 = *(const i32x4*)(vld);
        af1 = *(const i32x4*)(vld + 64);
        vld += 128;
      }
      __syncthreads();
    }
    // tail: PV(pair 30) reads Pt[0] (quant(30) wrote at iter 31); quant(31) -> Pt[1]
    acc[0] = MFMA_I8(af0pp, *(const i32x4*)(Pt[0][0] + pofs[0]), acc[0]);
    acc[1] = MFMA_I8(af0pp, *(const i32x4*)(Pt[0][0] + pofs[1]), acc[1]);
    acc[2] = MFMA_I8(af0pp, *(const i32x4*)(Pt[0][0] + pofs[2]), acc[2]);
    acc[3] = MFMA_I8(af0pp, *(const i32x4*)(Pt[0][0] + pofs[3]), acc[3]);
    acc[0] = MFMA_I8(af1pp, *(const i32x4*)(Pt[0][1] + pofs[0]), acc[0]);
    acc[1] = MFMA_I8(af1pp, *(const i32x4*)(Pt[0][1] + pofs[1]), acc[1]);
    acc[2] = MFMA_I8(af1pp, *(const i32x4*)(Pt[0][1] + pofs[2]), acc[2]);
    acc[3] = MFMA_I8(af1pp, *(const i32x4*)(Pt[0][1] + pofs[3]), acc[3]);
    {
      u32 wp0 = 0, wp1 = 0;
      #pragma unroll
      for (int r = 0; r < 4; ++r){
        float at0 = EXP2F(fmaf((float)(spA0[r] + spB0[r]), sc2, crn));
        float y0 = fminf(fmaxf(rintf(at0) + zw, 0.f), 255.f);
        wp0 = __builtin_amdgcn_cvt_pk_u8_f32(y0, (u32)r, wp0);
        float at1 = EXP2F(fmaf((float)(spA1[r] + spB1[r]), sc2, crn));
        float y1 = fminf(fmaxf(rintf(at1) + zw, 0.f), 255.f);
        wp1 = __builtin_amdgcn_cvt_pk_u8_f32(y1, (u32)r, wp1);
      }
      Pt[1][0][pdst] = wp0 ^ 0x80808080u;
      Pt[1][1][pdst] = wp1 ^ 0x80808080u;
    }
    __syncthreads();
    acc[0] = MFMA_I8(af0p, *(const i32x4*)(Pt[1][0] + pofs[0]), acc[0]);
    acc[1] = MFMA_I8(af0p, *(const i32x4*)(Pt[1][0] + pofs[1]), acc[1]);
    acc[2] = MFMA_I8(af0p, *(const i32x4*)(Pt[1][0] + pofs[2]), acc[2]);
    acc[3] = MFMA_I8(af0p, *(const i32x4*)(Pt[1][0] + pofs[3]), acc[3]);
    acc[0] = MFMA_I8(af1p, *(const i32x4*)(Pt[1][1] + pofs[0]), acc[0]);
    acc[1] = MFMA_I8(af1p, *(const i32x4*)(Pt[1][1] + pofs[1]), acc[1]);
    acc[2] = MFMA_I8(af1p, *(const i32x4*)(Pt[1][1] + pofs[2]), acc[2]);
    acc[3] = MFMA_I8(af1p, *(const i32x4*)(Pt[1][1] + pofs[3]), acc[3]);
  }

  float s = pdv[0] * pdw[0];
  float corr = s * (128.0f - zw);
  int c0 = w*16 + q*4;
  float cv[4];
  #pragma unroll
  for (int r = 0; r < 4; ++r) cv[r] = corr * (float)vsum[b*Cc + c0 + r];
  #pragma unroll
  for (int ns = 0; ns < 4; ++ns){
    int n = nt*64 + ns*16 + lo16;
    U64c Uh;
    #pragma unroll
    for (int r = 0; r < 4; ++r)
      Uh.u[r] = f2bf(s*(float)acc[ns][r] + cv[r]);
    *(uint2*)(h2 + ((size_t)b*Nn + n)*Cc + c0) = Uh.v;
  }
}

extern "C" void kernel_launch(void* const* d_in, const int* in_sizes, int n_in,
                              void* d_out, int out_size, void* d_ws, size_t ws_size,
                              hipStream_t stream){
  (void)in_sizes; (void)n_in; (void)out_size; (void)ws_size;
  const float* x   = (const float*)d_in[0];
  const float* gsc = (const float*)d_in[1];
  const float* gbi = (const float*)d_in[2];
  const float* wq  = (const float*)d_in[3];
  const float* bq  = (const float*)d_in[4];
  const float* wk  = (const float*)d_in[5];
  const float* bk  = (const float*)d_in[6];
  const float* wv  = (const float*)d_in[7];
  const float* bv  = (const float*)d_in[8];
  const float* wp  = (const float*)d_in[9];
  const float* bp  = (const float*)d_in[10];
  const float* dq  = (const float*)d_in[11];
  const float* zq  = (const float*)d_in[12];
  const float* dk  = (const float*)d_in[13];
  const float* zk  = (const float*)d_in[14];
  const float* dv  = (const float*)d_in[15];
  const float* zv  = (const float*)d_in[16];
  const float* dw  = (const float*)d_in[17];
  const float* zw  = (const float*)d_in[18];
  float* out = (float*)d_out;

  const size_t SZT = (size_t)Bb*Nn*Cc;
  u16* hT_hi = (u16*)d_ws;
  u16* hT_lo = hT_hi + SZT;
  u16* h2    = hT_lo + SZT;
  u8*  qT8   = (u8*)(h2 + SZT);
  u8*  kT8   = qT8 + SZT;
  u8*  v8    = kT8 + SZT;
  u16* WH    = (u16*)(v8 + SZT);
  u16* WL    = WH + 4*65536;
  float* mu  = (float*)(WL + 4*65536);
  float* rs  = mu + 128;
  u32*  stat = (u32*)(rs + 128);
  int*  vsum = (int*)(stat + 8);

  k_gn_stats<<<dim3(Bb*NGRP), 256, 0, stream>>>(x, mu, rs);
  k_wsplit<<<dim3(1024), 256, 0, stream>>>(wq, wk, wv, wp, WH, WL);
  k_gn_apply<<<dim3(Nn/64, Cc/64, Bb), 256, 0, stream>>>(x, gsc, gbi, mu, rs, hT_hi, hT_lo);

  k_convqkv<<<dim3(Nn/64, 4, Bb), 256, 0, stream>>>(WH, WL, hT_hi, hT_lo,
                                                    bq, bk, bv, dq, zq, dk, zk, dv, zv,
                                                    qT8, kT8, v8);

  hipMemsetAsync(stat, 0, 8*sizeof(u32), stream);
  k_normvs<<<dim3(128 + Bb*Cc), 256, 0, stream>>>(qT8, kT8, v8, stat, vsum);

  k_qpv<<<dim3(Nn/64, Bb), 1024, 0, stream>>>(qT8, kT8, v8, stat, dq, dk, dw, zw, vsum, dv, h2);

  k_conv<<<dim3(Nn/64, 4, Bb), 256, 0, stream>>>(WH, WL, h2, bp, x, out);
}

// Round 9
// 240.057 us; speedup vs baseline: 1.0804x; 1.0255x over previous
//
#include <hip/hip_runtime.h>

// QuantAttnBlock on gfx950, round 17: k_conv FUSED into k_qpv tail.
// Each k_qpv block owns h_out rows [nt*64, nt*64+64) x all 256 ch -- exactly
// k_conv's input tile. Tail: h_out -> LDS (k_conv swizzle, overlaid on Kt),
// barrier, proj GEMM (Wp hi/lo, per-kc weight loads), + x residual -> out.
// h2 global round-trip (16MB) and the k_conv dispatch are eliminated.
// Main loop identical to r16 (BK=128, 2-deep pipeline, V-direct).
// Numerics identical (verified absmax ~0.0234).

#define Bb 4
#define Cc 256
#define Nn 4096
#define NGRP 32
#define LOG2E 1.4426950408889634f

typedef unsigned short u16;
typedef unsigned int   u32;
typedef unsigned char  u8;
typedef __attribute__((ext_vector_type(8))) short bf16x8;
typedef __attribute__((ext_vector_type(4))) float f32x4;
typedef __attribute__((ext_vector_type(4))) int   i32x4;

#define MFMA16(a,b,c)    __builtin_amdgcn_mfma_f32_16x16x32_bf16((a),(b),(c),0,0,0)
#define MFMA_I8(a,b,c)   __builtin_amdgcn_mfma_i32_16x16x64_i8((a),(b),(c),0,0,0)
#define EXP2F(x)         __builtin_amdgcn_exp2f(x)

static __device__ __forceinline__ u16 f2bf(float x){
  u32 u = __float_as_uint(x);
  u += 0x7fffu + ((u >> 16) & 1u);
  return (u16)(u >> 16);
}
static __device__ __forceinline__ float bf2f(u16 h){ return __uint_as_float(((u32)h) << 16); }

union U64c { u16 u[4]; uint2 v; };

// ---------------- GroupNorm stats ----------------
__global__ __launch_bounds__(256) void k_gn_stats(const float* __restrict__ x,
                                                  float* __restrict__ mu, float* __restrict__ rs){
  int bg = blockIdx.x;
  const float4* p = (const float4*)(x + (size_t)bg * (8 * Nn));
  float s = 0.f, q = 0.f;
  for (int i = threadIdx.x; i < 8*Nn/4; i += 256){
    float4 v = p[i];
    s += v.x + v.y + v.z + v.w;
    q += v.x*v.x + v.y*v.y + v.z*v.z + v.w*v.w;
  }
  __shared__ float rsum[256], rsq[256];
  rsum[threadIdx.x] = s; rsq[threadIdx.x] = q;
  __syncthreads();
  for (int off = 128; off > 0; off >>= 1){
    if (threadIdx.x < off){ rsum[threadIdx.x] += rsum[threadIdx.x+off]; rsq[threadIdx.x] += rsq[threadIdx.x+off]; }
    __syncthreads();
  }
  if (threadIdx.x == 0){
    const float inv = 1.0f / (8*Nn);
    float m = rsum[0]*inv;
    float var = rsq[0]*inv - m*m;
    mu[bg] = m; rs[bg] = rsqrtf(var + 1e-6f);
  }
}

// ------------- weight split: 4 matrices f32 -> hi/lo bf16 -------------
__global__ __launch_bounds__(256) void k_wsplit(const float* __restrict__ wq, const float* __restrict__ wk,
                                                const float* __restrict__ wv, const float* __restrict__ wp,
                                                u16* __restrict__ WH, u16* __restrict__ WL){
  int gid = blockIdx.x*256 + threadIdx.x;
  int mat = gid >> 16, idx = gid & 65535;
  const float* src = (mat == 0) ? wq : (mat == 1) ? wk : (mat == 2) ? wv : wp;
  float w = src[idx];
  u16 h = f2bf(w);
  WH[gid] = h;
  WL[gid] = f2bf(w - bf2f(h));
}

// ------------- GroupNorm apply + transpose -> hT hi/lo [b][n][c] -------------
__global__ __launch_bounds__(256) void k_gn_apply(const float* __restrict__ x,
                                                  const float* __restrict__ gsc, const float* __restrict__ gbi,
                                                  const float* __restrict__ mu, const float* __restrict__ rs,
                                                  u16* __restrict__ hhi, u16* __restrict__ hlo){
  int nt = blockIdx.x, ct = blockIdx.y, b = blockIdx.z;
  int n0 = nt*64, c0 = ct*64;
  __shared__ float yt[64*65];
  __shared__ float sa[64], sb[64];
  int t = threadIdx.x;
  if (t < 64){
    int c = c0 + t;
    int bg = b*NGRP + (c >> 3);
    float a = rs[bg] * gsc[c];
    sa[t] = a;
    sb[t] = gbi[c] - mu[bg]*a;
  }
  __syncthreads();
  #pragma unroll
  for (int j = 0; j < 4; ++j){
    int id = t + j*256;
    int r = id >> 4, cq = id & 15;
    float4 v = *(const float4*)(x + ((size_t)b*Cc + c0 + r)*Nn + n0 + cq*4);
    float a = sa[r], bb = sb[r];
    yt[r*65 + cq*4 + 0] = v.x*a + bb;
    yt[r*65 + cq*4 + 1] = v.y*a + bb;
    yt[r*65 + cq*4 + 2] = v.z*a + bb;
    yt[r*65 + cq*4 + 3] = v.w*a + bb;
  }
  __syncthreads();
  int nl = t >> 2, cg = (t & 3) * 16;
  size_t base = ((size_t)b*Nn + n0 + nl)*Cc + c0 + cg;
  #pragma unroll
  for (int half = 0; half < 2; ++half){
    union { u16 u[8]; uint4 v; } Ph, Pl;
    #pragma unroll
    for (int u = 0; u < 8; ++u){
      float y = yt[(cg + half*8 + u)*65 + nl];
      u16 h = f2bf(y);
      Ph.u[u] = h; Pl.u[u] = f2bf(y - bf2f(h));
    }
    *(uint4*)(hhi + base + half*8) = Ph.v;
    *(uint4*)(hlo + base + half*8) = Pl.v;
  }
}

// ------------- Fused QKV conv GEMM (bf16 hi/lo, ~fp32 accurate) -------------
__global__ __launch_bounds__(256) void k_convqkv(const u16* __restrict__ WH, const u16* __restrict__ WL,
                                                 const u16* __restrict__ Hhi, const u16* __restrict__ Hlo,
                                                 const float* __restrict__ bq, const float* __restrict__ bk,
                                                 const float* __restrict__ bv,
                                                 const float* __restrict__ dq, const float* __restrict__ zq,
                                                 const float* __restrict__ dk, const float* __restrict__ zk,
                                                 const float* __restrict__ dv, const float* __restrict__ zv,
                                                 u8* __restrict__ qT8, u8* __restrict__ kT8,
                                                 u8* __restrict__ v8){
  int nt = blockIdx.x, ot = blockIdx.y, b = blockIdx.z;
  __shared__ u16 Lh[64*256], Ll[64*256];
  int t = threadIdx.x, lane = t & 63, wave = t >> 6;
  int lo16 = lane & 15, quad = lane >> 4;
  int o0 = ot*64 + wave*16;

  {
    const u16* hb = Hhi + ((size_t)b*Nn + nt*64) * 256;
    const u16* lb = Hlo + ((size_t)b*Nn + nt*64) * 256;
    #pragma unroll
    for (int j = 0; j < 8; ++j){
      int id = t + j*256;
      int r = id >> 5, ch = id & 31;
      int sw = (ch ^ (r & 15)) * 8;
      *(uint4*)(Lh + r*256 + sw) = *(const uint4*)(hb + (size_t)r*256 + ch*8);
      *(uint4*)(Ll + r*256 + sw) = *(const uint4*)(lb + (size_t)r*256 + ch*8);
    }
  }
  __syncthreads();

  const float* Bs[3] = {bq, bk, bv};
  const float* Dsr[3] = {dq, dk, dv};
  const float* Zs[3] = {zq, zk, zv};

  #pragma unroll
  for (int ws = 0; ws < 3; ++ws){
    bf16x8 awh[8], awl[8];
    {
      const u16* wbh = WH + (size_t)ws*65536 + (size_t)(o0 + lo16) * 256 + quad*8;
      const u16* wbl = WL + (size_t)ws*65536 + (size_t)(o0 + lo16) * 256 + quad*8;
      #pragma unroll
      for (int k = 0; k < 8; ++k){
        awh[k] = *(const bf16x8*)(wbh + k*32);
        awl[k] = *(const bf16x8*)(wbl + k*32);
      }
    }
    f32x4 zf = {0.f,0.f,0.f,0.f};
    f32x4 acc[4] = {zf, zf, zf, zf};
    #pragma unroll
    for (int k = 0; k < 8; ++k){
      #pragma unroll
      for (int ns = 0; ns < 4; ++ns){
        int r = ns*16 + lo16;
        int ph = ((k*4 + quad) ^ (r & 15)) * 8;
        bf16x8 bh = *(const bf16x8*)(Lh + r*256 + ph);
        bf16x8 bl = *(const bf16x8*)(Ll + r*256 + ph);
        acc[ns] = MFMA16(awh[k], bh, acc[ns]);
        acc[ns] = MFMA16(awl[k], bh, acc[ns]);
        acc[ns] = MFMA16(awh[k], bl, acc[ns]);
      }
    }
    float bia[4];
    #pragma unroll
    for (int r = 0; r < 4; ++r) bia[r] = Bs[ws][o0 + quad*4 + r];
    float z = Zs[ws][0]; float invd = 1.0f / Dsr[ws][0];

    if (ws < 2){
      u8* outT = (ws == 0) ? qT8 : kT8;
      #pragma unroll
      for (int ns = 0; ns < 4; ++ns){
        int n = nt*64 + ns*16 + lo16;
        u32 w = 0;
        #pragma unroll
        for (int r = 0; r < 4; ++r){
          float v = acc[ns][r] + bia[r];
          float xq = fminf(fmaxf(rintf(v*invd) + z, 0.f), 255.f);
          int qi = (int)rintf(xq - z);
          w |= ((u32)(qi & 255)) << (8*r);
        }
        *(u32*)(outT + ((size_t)b*Nn + n)*Cc + o0 + quad*4) = w;
      }
    } else {
      #pragma unroll
      for (int ns = 0; ns < 4; ++ns){
        int n = nt*64 + ns*16 + lo16;
        #pragma unroll
        for (int r = 0; r < 4; ++r){
          float v = acc[ns][r] + bia[r];
          float xq = fminf(fmaxf(rintf(v*invd) + z, 0.f), 255.f);
          int qi = (int)rintf(xq - z);
          v8[((size_t)b*Cc + o0 + quad*4 + r)*Nn + n] = (u8)(qi & 255);
        }
      }
    }
  }
}

// ------------- merged: row norm^2 max + vsum -------------
static __device__ __forceinline__ int sq4(u32 w){
  int s = 0;
  #pragma unroll
  for (int j = 0; j < 4; ++j){ int v = (int)((signed char)((w >> (8*j)) & 0xffu)); s += v*v; }
  return s;
}
static __device__ __forceinline__ int ssum4(u32 w){
  return ((int)(w << 24) >> 24) + ((int)(w << 16) >> 24) + ((int)(w << 8) >> 24) + ((int)w >> 24);
}
__global__ __launch_bounds__(256) void k_normvs(const u8* __restrict__ qT8, const u8* __restrict__ kT8,
                                                const u8* __restrict__ v8,
                                                u32* __restrict__ stat, int* __restrict__ vsum){
  if (blockIdx.x < 128){
    int gid = blockIdx.x*256 + threadIdx.x;
    int which = gid >> 14;
    int rid = gid & 16383;
    const u8* row = (which ? kT8 : qT8) + (size_t)rid * 256;
    u32 acc = 0;
    const uint4* p = (const uint4*)row;
    #pragma unroll
    for (int i = 0; i < 16; ++i){
      uint4 w = p[i];
      acc += (u32)(sq4(w.x) + sq4(w.y) + sq4(w.z) + sq4(w.w));
    }
    #pragma unroll
    for (int msk = 32; msk > 0; msk >>= 1){
      u32 o = (u32)__shfl_xor((int)acc, msk, 64);
      acc = acc > o ? acc : o;
    }
    if ((threadIdx.x & 63) == 0)
      atomicMax(&stat[which*4 + (rid >> 12)], acc);
  } else {
    int row = blockIdx.x - 128;
    uint4 w = *(const uint4*)(v8 + (size_t)row*Nn + threadIdx.x*16);
    int s = ssum4(w.x) + ssum4(w.y) + ssum4(w.z) + ssum4(w.w);
    #pragma unroll
    for (int msk = 1; msk < 64; msk <<= 1) s += __shfl_xor(s, msk, 64);
    __shared__ int r4[4];
    if ((threadIdx.x & 63) == 0) r4[threadIdx.x >> 6] = s;
    __syncthreads();
    if (threadIdx.x == 0) vsum[row] = r4[0] + r4[1] + r4[2] + r4[3];
  }
}

// ------------- fused attention + proj conv + residual: 1024 thr (16 waves),
// 64 q-rows per block. Main loop = r16 (BK=128, 2-deep pipeline, V direct).
// Tail: h_out tile -> LDS (k_conv swizzle, overlaid on Kt), proj GEMM vs
// Wp hi/lo, + x residual -> out. -------------
__global__ __launch_bounds__(1024) void k_qpv(const u8* __restrict__ qT8, const u8* __restrict__ kT8,
                                              const u8* __restrict__ v8,
                                              const u32* __restrict__ stat,
                                              const float* __restrict__ pdq, const float* __restrict__ pdk,
                                              const float* __restrict__ pdw, const float* __restrict__ pzw,
                                              const int* __restrict__ vsum,
                                              const float* __restrict__ pdv,
                                              const u16* __restrict__ WH, const u16* __restrict__ WL,
                                              const float* __restrict__ bp,
                                              const float* __restrict__ xres,
                                              float* __restrict__ outF){
  int nt = blockIdx.x, b = blockIdx.y;
  __shared__ alignas(16) u8  Kt[2][2][64*256];  // [iter-parity][tile-in-pair]
  __shared__ alignas(16) u32 Pt[2][2][64*16];   // [iter-parity][tile-in-pair]
  __shared__ float Lbuf[4][4][16];
  int t = threadIdx.x, lane = t & 63, w = t >> 6;
  int lo16 = lane & 15, q = lane >> 4;
  int ms = w & 3, nsq = w >> 2;

  float sc2 = pdq[0]*pdk[0]*0.0625f*LOG2E;
  float M2 = sc2 * sqrtf((float)stat[b] * (float)stat[4+b]);
  float zw = pzw[0];

  // Q B-fragments: rows n = nt*64 + nsq*16 + lo16
  i32x4 qf[4];
  {
    const u8* qb = qT8 + ((size_t)b*Nn + nt*64 + nsq*16 + lo16)*256;
    #pragma unroll
    for (int kk = 0; kk < 4; ++kk)
      qf[kk] = *(const i32x4*)(qb + kk*64 + q*16);
  }

  // K staging (1024 thr: 1 uint4 per tile, 2 tiles per iter)
  int krow = t >> 4, kch = t & 15;
  int kdst = krow*256 + ((kch ^ (krow & 15)) << 4);
  const u8* kb = kT8 + (size_t)b*Nn*256;

  int mrow = ms*16 + lo16;
  int kofs[4];
  #pragma unroll
  for (int kk = 0; kk < 4; ++kk) kofs[kk] = mrow*256 + (((kk*4 + q) ^ (mrow & 15)) << 4);

  // V direct: channel = w*16 + lo16 (16 waves cover 256 channels)
  const u8* vp = v8 + ((size_t)(b*Cc + w*16 + lo16))*Nn + q*16;

  // ---- pass 1: L(n) ----
  float lr = 0.f;
  {
    const u8* kld = kb + (size_t)krow*256 + kch*16;
    uint4 kr0 = *(const uint4*)(kld);
    uint4 kr1 = *(const uint4*)(kld + 16384);
    *(uint4*)(Kt[0][0] + kdst) = kr0;
    *(uint4*)(Kt[0][1] + kdst) = kr1;
    kld += 2*16384;
    kr0 = *(const uint4*)(kld);
    kr1 = *(const uint4*)(kld + 16384);
    kld += 2*16384;
    __syncthreads();
    i32x4 spA0, spB0, spA1, spB1;
    #pragma unroll 2
    for (int i = 0; i < 32; ++i){
      int cur = i & 1;
      i32x4 sA0 = {0,0,0,0}, sB0 = {0,0,0,0}, sA1 = {0,0,0,0}, sB1 = {0,0,0,0};
      sA0 = MFMA_I8(*(const i32x4*)(Kt[cur][0] + kofs[0]), qf[0], sA0);
      sB0 = MFMA_I8(*(const i32x4*)(Kt[cur][0] + kofs[1]), qf[1], sB0);
      sA1 = MFMA_I8(*(const i32x4*)(Kt[cur][1] + kofs[0]), qf[0], sA1);
      sB1 = MFMA_I8(*(const i32x4*)(Kt[cur][1] + kofs[1]), qf[1], sB1);
      sA0 = MFMA_I8(*(const i32x4*)(Kt[cur][0] + kofs[2]), qf[2], sA0);
      sB0 = MFMA_I8(*(const i32x4*)(Kt[cur][0] + kofs[3]), qf[3], sB0);
      sA1 = MFMA_I8(*(const i32x4*)(Kt[cur][1] + kofs[2]), qf[2], sA1);
      sB1 = MFMA_I8(*(const i32x4*)(Kt[cur][1] + kofs[3]), qf[3], sB1);
      if (i < 31){
        *(uint4*)(Kt[cur ^ 1][0] + kdst) = kr0;
        *(uint4*)(Kt[cur ^ 1][1] + kdst) = kr1;
        if (i < 30){
          kr0 = *(const uint4*)(kld);
          kr1 = *(const uint4*)(kld + 16384);
          kld += 2*16384;
        }
      }
      if (i > 0){
        #pragma unroll
        for (int r = 0; r < 4; ++r){
          lr += EXP2F(fmaf((float)(spA0[r] + spB0[r]), sc2, -M2));
          lr += EXP2F(fmaf((float)(spA1[r] + spB1[r]), sc2, -M2));
        }
      }
      spA0 = sA0; spB0 = sB0; spA1 = sA1; spB1 = sB1;
      __syncthreads();
    }
    #pragma unroll
    for (int r = 0; r < 4; ++r){
      lr += EXP2F(fmaf((float)(spA0[r] + spB0[r]), sc2, -M2));
      lr += EXP2F(fmaf((float)(spA1[r] + spB1[r]), sc2, -M2));
    }
  }
  lr += __shfl_xor(lr, 16, 64);
  lr += __shfl_xor(lr, 32, 64);
  if (lane < 16) Lbuf[nsq][ms][lo16] = lr;
  __syncthreads();
  float Ls = Lbuf[nsq][0][lo16] + Lbuf[nsq][1][lo16] + Lbuf[nsq][2][lo16] + Lbuf[nsq][3][lo16];
  float crn = __log2f(1.0f / (pdw[0] * Ls)) - M2;

  // ---- pass 2: 2-deep pipeline over supertiles ----
  i32x4 zi = {0,0,0,0};
  i32x4 acc[4] = {zi,zi,zi,zi};
  int nrow = nsq*16 + lo16;
  int pdst = nrow*16 + ((ms ^ (nrow & 3) ^ ((nrow >> 2) & 3)) << 2) + q;
  int pofs[4];
  #pragma unroll
  for (int ns = 0; ns < 4; ++ns){
    int pr = ns*16 + lo16;
    pofs[ns] = pr*16 + ((q ^ (pr & 3) ^ ((pr >> 2) & 3)) << 2);
  }
  {
    const u8* kld = kb + (size_t)krow*256 + kch*16;
    uint4 kr0 = *(const uint4*)(kld);
    uint4 kr1 = *(const uint4*)(kld + 16384);
    *(uint4*)(Kt[0][0] + kdst) = kr0;
    *(uint4*)(Kt[0][1] + kdst) = kr1;
    kld += 2*16384;
    kr0 = *(const uint4*)(kld);
    kr1 = *(const uint4*)(kld + 16384);
    kld += 2*16384;
    const u8* vld = vp + 128;
    i32x4 af0 = *(const i32x4*)(vp);          // V tile 0
    i32x4 af1 = *(const i32x4*)(vp + 64);     // V tile 1
    i32x4 af0p, af1p, af0pp, af1pp;
    i32x4 spA0, spB0, spA1, spB1;
    __syncthreads();
    #pragma unroll 2
    for (int i = 0; i < 32; ++i){
      int cur = i & 1;
      // QK(pair i): consumed at iter i+1
      i32x4 sA0 = {0,0,0,0}, sB0 = {0,0,0,0}, sA1 = {0,0,0,0}, sB1 = {0,0,0,0};
      sA0 = MFMA_I8(*(const i32x4*)(Kt[cur][0] + kofs[0]), qf[0], sA0);
      sB0 = MFMA_I8(*(const i32x4*)(Kt[cur][0] + kofs[1]), qf[1], sB0);
      sA1 = MFMA_I8(*(const i32x4*)(Kt[cur][1] + kofs[0]), qf[0], sA1);
      sB1 = MFMA_I8(*(const i32x4*)(Kt[cur][1] + kofs[1]), qf[1], sB1);
      sA0 = MFMA_I8(*(const i32x4*)(Kt[cur][0] + kofs[2]), qf[2], sA0);
      sB0 = MFMA_I8(*(const i32x4*)(Kt[cur][0] + kofs[3]), qf[3], sB0);
      sA1 = MFMA_I8(*(const i32x4*)(Kt[cur][1] + kofs[2]), qf[2], sA1);
      sB1 = MFMA_I8(*(const i32x4*)(Kt[cur][1] + kofs[3]), qf[3], sB1);
      // stage K(pair i+1)
      if (i < 31){
        *(uint4*)(Kt[cur ^ 1][0] + kdst) = kr0;
        *(uint4*)(Kt[cur ^ 1][1] + kdst) = kr1;
        if (i < 30){
          kr0 = *(const uint4*)(kld);
          kr1 = *(const uint4*)(kld + 16384);
          kld += 2*16384;
        }
      }
      // PV(pair i-2): Pt[cur] (written at iter i-1, pre-barrier), af*pp
      if (i > 1){
        acc[0] = MFMA_I8(af0pp, *(const i32x4*)(Pt[cur][0] + pofs[0]), acc[0]);
        acc[1] = MFMA_I8(af0pp, *(const i32x4*)(Pt[cur][0] + pofs[1]), acc[1]);
        acc[2] = MFMA_I8(af0pp, *(const i32x4*)(Pt[cur][0] + pofs[2]), acc[2]);
        acc[3] = MFMA_I8(af0pp, *(const i32x4*)(Pt[cur][0] + pofs[3]), acc[3]);
        acc[0] = MFMA_I8(af1pp, *(const i32x4*)(Pt[cur][1] + pofs[0]), acc[0]);
        acc[1] = MFMA_I8(af1pp, *(const i32x4*)(Pt[cur][1] + pofs[1]), acc[1]);
        acc[2] = MFMA_I8(af1pp, *(const i32x4*)(Pt[cur][1] + pofs[2]), acc[2]);
        acc[3] = MFMA_I8(af1pp, *(const i32x4*)(Pt[cur][1] + pofs[3]), acc[3]);
      }
      // quant(pair i-1) -> Pt[cur^1][0/1]
      if (i > 0){
        u32 wp0 = 0, wp1 = 0;
        #pragma unroll
        for (int r = 0; r < 4; ++r){
          float at0 = EXP2F(fmaf((float)(spA0[r] + spB0[r]), sc2, crn));
          float y0 = fminf(fmaxf(rintf(at0) + zw, 0.f), 255.f);
          wp0 = __builtin_amdgcn_cvt_pk_u8_f32(y0, (u32)r, wp0);
          float at1 = EXP2F(fmaf((float)(spA1[r] + spB1[r]), sc2, crn));
          float y1 = fminf(fmaxf(rintf(at1) + zw, 0.f), 255.f);
          wp1 = __builtin_amdgcn_cvt_pk_u8_f32(y1, (u32)r, wp1);
        }
        Pt[cur ^ 1][0][pdst] = wp0 ^ 0x80808080u;
        Pt[cur ^ 1][1][pdst] = wp1 ^ 0x80808080u;
      }
      // rotate
      spA0 = sA0; spB0 = sB0; spA1 = sA1; spB1 = sB1;
      af0pp = af0p; af0p = af0; af1pp = af1p; af1p = af1;
      if (i < 31){
        af0 = *(const i32x4*)(vld);
        af1 = *(const i32x4*)(vld + 64);
        vld += 128;
      }
      __syncthreads();
    }
    // tail: PV(pair 30) reads Pt[0]; quant(31) -> Pt[1]
    acc[0] = MFMA_I8(af0pp, *(const i32x4*)(Pt[0][0] + pofs[0]), acc[0]);
    acc[1] = MFMA_I8(af0pp, *(const i32x4*)(Pt[0][0] + pofs[1]), acc[1]);
    acc[2] = MFMA_I8(af0pp, *(const i32x4*)(Pt[0][0] + pofs[2]), acc[2]);
    acc[3] = MFMA_I8(af0pp, *(const i32x4*)(Pt[0][0] + pofs[3]), acc[3]);
    acc[0] = MFMA_I8(af1pp, *(const i32x4*)(Pt[0][1] + pofs[0]), acc[0]);
    acc[1] = MFMA_I8(af1pp, *(const i32x4*)(Pt[0][1] + pofs[1]), acc[1]);
    acc[2] = MFMA_I8(af1pp, *(const i32x4*)(Pt[0][1] + pofs[2]), acc[2]);
    acc[3] = MFMA_I8(af1pp, *(const i32x4*)(Pt[0][1] + pofs[3]), acc[3]);
    {
      u32 wp0 = 0, wp1 = 0;
      #pragma unroll
      for (int r = 0; r < 4; ++r){
        float at0 = EXP2F(fmaf((float)(spA0[r] + spB0[r]), sc2, crn));
        float y0 = fminf(fmaxf(rintf(at0) + zw, 0.f), 255.f);
        wp0 = __builtin_amdgcn_cvt_pk_u8_f32(y0, (u32)r, wp0);
        float at1 = EXP2F(fmaf((float)(spA1[r] + spB1[r]), sc2, crn));
        float y1 = fminf(fmaxf(rintf(at1) + zw, 0.f), 255.f);
        wp1 = __builtin_amdgcn_cvt_pk_u8_f32(y1, (u32)r, wp1);
      }
      Pt[1][0][pdst] = wp0 ^ 0x80808080u;
      Pt[1][1][pdst] = wp1 ^ 0x80808080u;
    }
    __syncthreads();
    acc[0] = MFMA_I8(af0p, *(const i32x4*)(Pt[1][0] + pofs[0]), acc[0]);
    acc[1] = MFMA_I8(af0p, *(const i32x4*)(Pt[1][0] + pofs[1]), acc[1]);
    acc[2] = MFMA_I8(af0p, *(const i32x4*)(Pt[1][0] + pofs[2]), acc[2]);
    acc[3] = MFMA_I8(af0p, *(const i32x4*)(Pt[1][0] + pofs[3]), acc[3]);
    acc[0] = MFMA_I8(af1p, *(const i32x4*)(Pt[1][1] + pofs[0]), acc[0]);
    acc[1] = MFMA_I8(af1p, *(const i32x4*)(Pt[1][1] + pofs[1]), acc[1]);
    acc[2] = MFMA_I8(af1p, *(const i32x4*)(Pt[1][1] + pofs[2]), acc[2]);
    acc[3] = MFMA_I8(af1p, *(const i32x4*)(Pt[1][1] + pofs[3]), acc[3]);
  }

  // ---- fused proj conv + residual ----
  // h_out -> LDS tile Ht[64][256] bf16, k_conv swizzle per 128-half:
  // dst = r*256 + kc*128 + ((ch8 ^ (r&7))<<3) + (c&7)
  u16* Ht = (u16*)Kt;   // overlay (Kt reads finished >=2 barriers ago)
  {
    float s = pdv[0] * pdw[0];
    float corr = s * (128.0f - zw);
    int c0 = w*16 + q*4;
    int kc0 = c0 >> 7;
    int ch8 = (c0 >> 3) & 15;
    int c4  = c0 & 7;
    float cv[4];
    #pragma unroll
    for (int r = 0; r < 4; ++r) cv[r] = corr * (float)vsum[b*Cc + c0 + r];
    #pragma unroll
    for (int ns = 0; ns < 4; ++ns){
      int rrow = ns*16 + lo16;
      U64c Uh;
      #pragma unroll
      for (int r = 0; r < 4; ++r)
        Uh.u[r] = f2bf(s*(float)acc[ns][r] + cv[r]);
      *(uint2*)(Ht + rrow*256 + kc0*128 + ((ch8 ^ (rrow & 7)) << 3) + c4) = Uh.v;
    }
  }
  __syncthreads();
  // proj GEMM: wave w -> output channels w*16 + q*4 + r
  {
    f32x4 zf = {0.f,0.f,0.f,0.f};
    f32x4 acc2[4] = {zf, zf, zf, zf};
    const u16* wbh = WH + (size_t)3*65536 + (size_t)(w*16 + lo16)*256 + q*8;
    const u16* wbl = WL + (size_t)3*65536 + (size_t)(w*16 + lo16)*256 + q*8;
    #pragma unroll
    for (int kc = 0; kc < 2; ++kc){
      bf16x8 ah[4], al[4];
      #pragma unroll
      for (int k4 = 0; k4 < 4; ++k4){
        ah[k4] = *(const bf16x8*)(wbh + kc*128 + k4*32);
        al[k4] = *(const bf16x8*)(wbl + kc*128 + k4*32);
      }
      #pragma unroll
      for (int k4 = 0; k4 < 4; ++k4){
        #pragma unroll
        for (int ns = 0; ns < 4; ++ns){
          int rrow = ns*16 + lo16;
          bf16x8 bh = *(const bf16x8*)(Ht + rrow*256 + kc*128 + (((k4*4 + q) ^ (rrow & 7)) << 3));
          acc2[ns] = MFMA16(ah[k4], bh, acc2[ns]);
          acc2[ns] = MFMA16(al[k4], bh, acc2[ns]);
        }
      }
    }
    float bia[4];
    #pragma unroll
    for (int r = 0; r < 4; ++r) bia[r] = bp[w*16 + q*4 + r];
    #pragma unroll
    for (int ns = 0; ns < 4; ++ns){
      int n = nt*64 + ns*16 + lo16;
      #pragma unroll
      for (int r = 0; r < 4; ++r){
        size_t a = ((size_t)b*Cc + w*16 + q*4 + r)*Nn + n;
        outF[a] = xres[a] + acc2[ns][r] + bia[r];
      }
    }
  }
}

extern "C" void kernel_launch(void* const* d_in, const int* in_sizes, int n_in,
                              void* d_out, int out_size, void* d_ws, size_t ws_size,
                              hipStream_t stream){
  (void)in_sizes; (void)n_in; (void)out_size; (void)ws_size;
  const float* x   = (const float*)d_in[0];
  const float* gsc = (const float*)d_in[1];
  const float* gbi = (const float*)d_in[2];
  const float* wq  = (const float*)d_in[3];
  const float* bq  = (const float*)d_in[4];
  const float* wk  = (const float*)d_in[5];
  const float* bk  = (const float*)d_in[6];
  const float* wv  = (const float*)d_in[7];
  const float* bv  = (const float*)d_in[8];
  const float* wp  = (const float*)d_in[9];
  const float* bp  = (const float*)d_in[10];
  const float* dq  = (const float*)d_in[11];
  const float* zq  = (const float*)d_in[12];
  const float* dk  = (const float*)d_in[13];
  const float* zk  = (const float*)d_in[14];
  const float* dv  = (const float*)d_in[15];
  const float* zv  = (const float*)d_in[16];
  const float* dw  = (const float*)d_in[17];
  const float* zw  = (const float*)d_in[18];
  float* out = (float*)d_out;

  const size_t SZT = (size_t)Bb*Nn*Cc;
  u16* hT_hi = (u16*)d_ws;
  u16* hT_lo = hT_hi + SZT;
  u16* h2    = hT_lo + SZT;   // unused (kept for layout stability)
  u8*  qT8   = (u8*)(h2 + SZT);
  u8*  kT8   = qT8 + SZT;
  u8*  v8    = kT8 + SZT;
  u16* WH    = (u16*)(v8 + SZT);
  u16* WL    = WH + 4*65536;
  float* mu  = (float*)(WL + 4*65536);
  float* rs  = mu + 128;
  u32*  stat = (u32*)(rs + 128);
  int*  vsum = (int*)(stat + 8);

  k_gn_stats<<<dim3(Bb*NGRP), 256, 0, stream>>>(x, mu, rs);
  k_wsplit<<<dim3(1024), 256, 0, stream>>>(wq, wk, wv, wp, WH, WL);
  k_gn_apply<<<dim3(Nn/64, Cc/64, Bb), 256, 0, stream>>>(x, gsc, gbi, mu, rs, hT_hi, hT_lo);

  k_convqkv<<<dim3(Nn/64, 4, Bb), 256, 0, stream>>>(WH, WL, hT_hi, hT_lo,
                                                    bq, bk, bv, dq, zq, dk, zk, dv, zv,
                                                    qT8, kT8, v8);

  hipMemsetAsync(stat, 0, 8*sizeof(u32), stream);
  k_normvs<<<dim3(128 + Bb*Cc), 256, 0, stream>>>(qT8, kT8, v8, stat, vsum);

  k_qpv<<<dim3(Nn/64, Bb), 1024, 0, stream>>>(qT8, kT8, v8, stat, dq, dk, dw, zw, vsum, dv,
                                              WH, WL, bp, x, out);
}